// Round 11
// baseline (50.047 us; speedup 1.0000x reference)
//
#include <hip/hip_runtime.h>
#include <math.h>

// SMEFTNet forward. B=128, N=128, H=16.  TWO kernels.
// K1 "fused": 256 blocks (batch, ihalf) x 1024 thr (16 waves), 1 block/CU.
//   Phase 0: conv0 for ALL 128 nodes of the batch (duplicated across the
//   batch's two blocks -> zero cross-block deps). Outputs to LDS.
//   Phase 1: conv1 for this block's 64-node half, j-data from LDS.
//   Phase 2: readout partials -> part[block][20].
// K2: 128 blocks x 64 thr: combine 2 partials, 16->32->32->1 MLP -> out.
// R10 bug fixed: launch_bounds(1024,4) demanded 64 waves/CU -> VGPR clamped
// to 64 -> 36 MB scratch spills. Now (1024,1): VGPR cap 256, no spill.

#define BB 128
#define NN 128
#define BN (BB * NN)

typedef float f32x2 __attribute__((ext_vector_type(2)));

__device__ __forceinline__ f32x2 pk2(float s) { f32x2 r; r[0] = s; r[1] = s; return r; }
__device__ __forceinline__ f32x2 pkfma(f32x2 a, f32x2 b, f32x2 c) {
    return __builtin_elementwise_fma(a, b, c);
}
__device__ __forceinline__ f32x2 pkmax(f32x2 a, f32x2 b) {
    return __builtin_elementwise_max(a, b);
}

template <int CTRL>
__device__ __forceinline__ float dpp_add(float x) {
    int tmp = __builtin_amdgcn_update_dpp(0, __float_as_int(x), CTRL, 0xF, 0xF, true);
    return x + __int_as_float(tmp);
}

// Sum within each 16-lane row; result valid in lane (l|15) of each row.
__device__ __forceinline__ float grp16_sum(float x) {
    x = dpp_add<0xB1>(x);   // quad_perm [1,0,3,2]
    x = dpp_add<0x4E>(x);   // quad_perm [2,3,0,1]
    x = dpp_add<0x114>(x);  // row_shr:4
    x = dpp_add<0x118>(x);  // row_shr:8
    return x;
}

__device__ __forceinline__ float bcast_grp(float x, int bidx) {
    return __int_as_float(__builtin_amdgcn_ds_bpermute(bidx, __float_as_int(x)));
}

__device__ __forceinline__ f32x2 grp16_red2(f32x2 x, int bidx) {
    f32x2 r;
    r[0] = bcast_grp(grp16_sum(x[0]), bidx);
    r[1] = bcast_grp(grp16_sum(x[1]), bidx);
    return r;
}

// ---------------- K1: fused conv0 + conv1 + block partials ----------------
__global__ __launch_bounds__(1024, 1) void fused_kernel(
    const float* __restrict__ pt,    // (B,N)
    const float* __restrict__ ang,   // (B,N,2)
    const float* __restrict__ w0,    // c0_w0 (5,16)
    const float* __restrict__ b0,    // c0_b0 (16)
    const float* __restrict__ w1,    // c0_w1 (16,17)
    const float* __restrict__ b1,    // c0_b1 (17)
    const float* __restrict__ nw0,   // c1_w0 (50,16)
    const float* __restrict__ nb0,   // c1_b0 (16)
    const float* __restrict__ nw1,   // c1_w1 (16,17)
    const float* __restrict__ nb1,   // c1_b1 (17)
    float* __restrict__ part)        // (256,20)
{
    const int tid   = threadIdx.x;
    const int lane  = tid & 63;
    const int wid   = tid >> 6;        // 0..15
    const int t     = lane & 15;
    const int g     = lane >> 4;
    const int batch = blockIdx.x >> 1;
    const int ihalf = blockIdx.x & 1;
    const int nbase = batch * NN;

    __shared__ float u_lds[128][20];
    __shared__ float v_lds[128][20];
    __shared__ float4 rec_lds[128];
    __shared__ float hls[64][20];
    __shared__ float Ap2[16][20];

    // ---- phase 0: conv0 for all 128 nodes (2 rounds of 64) ----
    float2 ajv[8]; float abszj[8], ivjr[8];
    #pragma unroll
    for (int jj = 0; jj < 8; ++jj) {
        ajv[jj] = ((const float2*)ang)[nbase + jj * 16 + t];
        const float r2 = fmaf(ajv[jj].x, ajv[jj].x, ajv[jj].y * ajv[jj].y);
        abszj[jj] = __builtin_amdgcn_sqrtf(r2);
        ivjr[jj]  = __builtin_amdgcn_rsqf(r2);
    }
    // layer-0 constants (uniform addresses -> scalar loads)
    f32x2 q02[8], wc2[8], ws2[8], wac2[8], bb2[8];
    #pragma unroll
    for (int p = 0; p < 8; ++p) {
        f32x2 wa  = *(const f32x2*)(w0 + 2 * p);
        f32x2 wb  = *(const f32x2*)(w0 + 16 + 2 * p);
        f32x2 wcv = *(const f32x2*)(w0 + 32 + 2 * p);
        bb2[p]  = *(const f32x2*)(b0 + 2 * p);
        wac2[p] = wa - wcv;                      // Wa-Wc
        q02[p]  = wb + wcv;                      // Wb+Wc
        wc2[p]  = *(const f32x2*)(w0 + 48 + 2 * p);
        ws2[p]  = *(const f32x2*)(w0 + 64 + 2 * p);
    }

    const int o = lane & 31;
    const int kk = o & 15;
    const bool isU = (o < 16);
    const int bidx = (lane | 15) << 2;

    // proj weights (hoisted: same for both rounds)
    float wkp[16];
    {
        const int off = isU ? 0 : 256;
        #pragma unroll
        for (int c = 0; c < 16; ++c) {
            const float a_ = nw0[off + c * 16 + kk];
            const float c_ = nw0[512 + c * 16 + kk];
            wkp[c] = isU ? (a_ - c_) : (a_ + c_);
        }
    }
    const float accb = isU ? nb0[kk] : 0.0f;

    #pragma unroll
    for (int r = 0; r < 2; ++r) {
        const int nlr    = wid * 4 + g;          // round-local node [0,64)
        const int nlocal = r * 64 + nlr;
        const int ni     = nbase + nlocal;

        const float2 ai = ((const float2*)ang)[ni];
        const float r2i = fmaf(ai.x, ai.x, ai.y * ai.y);
        const float abszi = __builtin_amdgcn_sqrtf(r2i);
        const float invi  = __builtin_amdgcn_rsqf(r2i);

        f32x2 u0b2[8];
        #pragma unroll
        for (int p = 0; p < 8; ++p) u0b2[p] = pkfma(pk2(abszi), wac2[p], bb2[p]);

        f32x2 A2[8];
        #pragma unroll
        for (int p = 0; p < 8; ++p) A2[p] = pk2(0.0f);
        float degf = 0.0f;

        #pragma unroll
        for (int jj = 0; jj < 8; ++jj) {
            const float2 aj = ajv[jj];
            const float dre = ai.x - aj.x, dim = ai.y - aj.y;
            const float d2 = fmaf(dre, dre, dim * dim);
            const float adjf = (d2 <= 0.16f) ? 1.0f : 0.0f;
            degf += adjf;
            const float inv = fminf(invi * ivjr[jj], 1e12f);
            const f32x2 cos2 = pk2(fmaf(ai.x, aj.x, ai.y * aj.y) * inv);
            const f32x2 sin2 = pk2(fmaf(ai.y, aj.x, -(ai.x * aj.y)) * inv);
            const f32x2 ab2 = pk2(abszj[jj]);
            const f32x2 adj2 = pk2(adjf);
            #pragma unroll
            for (int p = 0; p < 8; ++p) {
                f32x2 z = pkfma(ab2, q02[p], u0b2[p]);
                z = pkfma(cos2, wc2[p], z);
                z = pkfma(sin2, ws2[p], z);
                f32x2 a = pkmax(z, z * 0.01f);
                A2[p] = pkfma(a, adj2, A2[p]);
            }
        }

        f32x2 Ak2[8];
        #pragma unroll
        for (int p = 0; p < 8; ++p) Ak2[p] = grp16_red2(A2[p], bidx);
        const float invdeg = __builtin_amdgcn_rcpf(bcast_grp(grp16_sum(degf), bidx));

        // 2nd MLP layer (epilogue loads: channel t + gamma column)
        f32x2 s2 = pk2(0.0f), g2 = pk2(0.0f);
        #pragma unroll
        for (int p = 0; p < 8; ++p) {
            f32x2 wr; wr[0] = w1[(2 * p) * 17 + t];  wr[1] = w1[(2 * p + 1) * 17 + t];
            f32x2 wg; wg[0] = w1[(2 * p) * 17 + 16]; wg[1] = w1[(2 * p + 1) * 17 + 16];
            s2 = pkfma(Ak2[p], wr, s2);
            g2 = pkfma(Ak2[p], wg, g2);
        }
        const float mt    = fmaf(s2[0] + s2[1], invdeg, b1[t]);
        const float gamma = fmaf(g2[0] + g2[1], invdeg, b1[16]);

        // rotation (v_cos/v_sin take revolutions); norm preserved -> store invi
        {
            const float gf = gamma - floorf(gamma);
            const float cs = __builtin_amdgcn_cosf(gf);
            const float sn = __builtin_amdgcn_sinf(gf);
            if (t == 0) {
                const float re2 = cs * ai.x - sn * ai.y;
                const float im2 = fmaf(sn, ai.x, cs * ai.y);
                rec_lds[nlocal] = make_float4(re2, im2, invi, 0.0f);
            }
        }

        hls[nlr][t] = mt;   // same-wave exchange (in-order, no barrier)

        #pragma unroll
        for (int ps = 0; ps < 2; ++ps) {
            const int nl = (lane >> 5) + 2 * ps;
            const int node = wid * 4 + nl;       // round-local
            float acc = accb;
            #pragma unroll
            for (int c = 0; c < 16; ++c) acc = fmaf(hls[node][c], wkp[c], acc);
            if (isU) u_lds[r * 64 + node][kk] = acc;
            else     v_lds[r * 64 + node][kk] = acc;
        }
    }
    __syncthreads();

    // ---- phase 1: conv1 for this block's 64-node half ----
    const int nlocal1 = ihalf * 64 + wid * 4 + g;
    const int ni1 = nbase + nlocal1;
    const float4 a4 = rec_lds[nlocal1];
    const float rei = a4.x, imi = a4.y, invi1 = a4.z;
    const float ptf = pt[ni1];

    f32x2 u0b2[8];
    {
        const float4* ug = (const float4*)&u_lds[nlocal1][0];
        float4 q0 = ug[0], q1 = ug[1], q2 = ug[2], q3 = ug[3];
        u0b2[0][0] = q0.x; u0b2[0][1] = q0.y; u0b2[1][0] = q0.z; u0b2[1][1] = q0.w;
        u0b2[2][0] = q1.x; u0b2[2][1] = q1.y; u0b2[3][0] = q1.z; u0b2[3][1] = q1.w;
        u0b2[4][0] = q2.x; u0b2[4][1] = q2.y; u0b2[5][0] = q2.z; u0b2[5][1] = q2.w;
        u0b2[6][0] = q3.x; u0b2[6][1] = q3.y; u0b2[7][0] = q3.z; u0b2[7][1] = q3.w;
    }
    f32x2 wc1[8], ws1[8];   // uniform -> scalar loads
    #pragma unroll
    for (int p = 0; p < 8; ++p) {
        wc1[p] = *(const f32x2*)(nw0 + 768 + 2 * p);
        ws1[p] = *(const f32x2*)(nw0 + 784 + 2 * p);
    }

    f32x2 A2[8];
    #pragma unroll
    for (int p = 0; p < 8; ++p) A2[p] = pk2(0.0f);
    float degf = 0.0f;

    #pragma unroll 4
    for (int jj = 0; jj < 8; ++jj) {
        const int j = jj * 16 + t;
        const float4 rj = rec_lds[j];
        f32x2 vj2[8];
        {
            const float4* vg = (const float4*)&v_lds[j][0];
            float4 q0 = vg[0], q1 = vg[1], q2 = vg[2], q3 = vg[3];
            vj2[0][0] = q0.x; vj2[0][1] = q0.y; vj2[1][0] = q0.z; vj2[1][1] = q0.w;
            vj2[2][0] = q1.x; vj2[2][1] = q1.y; vj2[3][0] = q1.z; vj2[3][1] = q1.w;
            vj2[4][0] = q2.x; vj2[4][1] = q2.y; vj2[5][0] = q2.z; vj2[5][1] = q2.w;
            vj2[6][0] = q3.x; vj2[6][1] = q3.y; vj2[7][0] = q3.z; vj2[7][1] = q3.w;
        }
        const float dre = rei - rj.x, dim = imi - rj.y;
        const float d2 = fmaf(dre, dre, dim * dim);
        const float adjf = (d2 <= 0.16f) ? 1.0f : 0.0f;
        degf += adjf;
        const float inv = fminf(invi1 * rj.z, 1e12f);
        const f32x2 cos2 = pk2(fmaf(rei, rj.x, imi * rj.y) * inv);
        const f32x2 sin2 = pk2(fmaf(imi, rj.x, -(rei * rj.y)) * inv);
        const f32x2 adj2 = pk2(adjf);
        #pragma unroll
        for (int p = 0; p < 8; ++p) {
            f32x2 z = u0b2[p] + vj2[p];
            z = pkfma(cos2, wc1[p], z);
            z = pkfma(sin2, ws1[p], z);
            f32x2 a = pkmax(z, z * 0.01f);
            A2[p] = pkfma(a, adj2, A2[p]);
        }
    }

    f32x2 Ak2[8];
    #pragma unroll
    for (int p = 0; p < 8; ++p) Ak2[p] = grp16_red2(A2[p], bidx);
    const float invdeg = __builtin_amdgcn_rcpf(bcast_grp(grp16_sum(degf), bidx));

    f32x2 s2 = pk2(0.0f), g2 = pk2(0.0f);
    #pragma unroll
    for (int p = 0; p < 8; ++p) {
        f32x2 wr; wr[0] = nw1[(2 * p) * 17 + t];  wr[1] = nw1[(2 * p + 1) * 17 + t];
        f32x2 wg; wg[0] = nw1[(2 * p) * 17 + 16]; wg[1] = nw1[(2 * p + 1) * 17 + 16];
        s2 = pkfma(Ak2[p], wr, s2);
        g2 = pkfma(Ak2[p], wg, g2);
    }
    const float mt    = fmaf(s2[0] + s2[1], invdeg, nb1[t]);
    const float gamma = fmaf(g2[0] + g2[1], invdeg, nb1[16]);

    const float gf = gamma - floorf(gamma);
    const float cs = __builtin_amdgcn_cosf(gf);
    const float sn = __builtin_amdgcn_sinf(gf);
    const float re2 = cs * rei - sn * imi;
    const float im2 = fmaf(sn, rei, cs * imi);

    // ---- phase 2: readout partials ----
    float pm  = ptf * mt;
    float pre = ptf * re2;
    float pim = ptf * im2;
    float ppt = ptf;
    pm  += __int_as_float(__builtin_amdgcn_ds_swizzle(__float_as_int(pm),  0x401F));
    pre += __int_as_float(__builtin_amdgcn_ds_swizzle(__float_as_int(pre), 0x401F));
    pim += __int_as_float(__builtin_amdgcn_ds_swizzle(__float_as_int(pim), 0x401F));
    ppt += __int_as_float(__builtin_amdgcn_ds_swizzle(__float_as_int(ppt), 0x401F));
    pm  += __shfl_xor(pm, 32);
    pre += __shfl_xor(pre, 32);
    pim += __shfl_xor(pim, 32);
    ppt += __shfl_xor(ppt, 32);

    if (lane < 16)       Ap2[wid][lane] = pm;
    else if (lane == 16) Ap2[wid][16] = pre;
    else if (lane == 17) Ap2[wid][17] = pim;
    else if (lane == 18) Ap2[wid][18] = ppt;
    __syncthreads();

    if (wid == 0 && lane < 19) {
        float s0 = 0.0f, s1 = 0.0f, s2_ = 0.0f, s3 = 0.0f;
        #pragma unroll
        for (int w = 0; w < 16; w += 4) {
            s0 += Ap2[w + 0][lane];
            s1 += Ap2[w + 1][lane];
            s2_ += Ap2[w + 2][lane];
            s3 += Ap2[w + 3][lane];
        }
        part[(size_t)blockIdx.x * 20 + lane] = (s0 + s1) + (s2_ + s3);
    }
}

// ---------------- K2: final readout (1 wave per batch) ----------------
__global__ __launch_bounds__(64) void readout_kernel(
    const float* __restrict__ part,  // (256,20)
    const float* __restrict__ w0, const float* __restrict__ b0,  // (16,32),(32)
    const float* __restrict__ w1, const float* __restrict__ b1,  // (32,32),(32)
    const float* __restrict__ w2, const float* __restrict__ b2,  // (32,1),(1)
    float* __restrict__ out) {
    const int b = blockIdx.x;
    const int t = threadIdx.x;

    __shared__ float sb[19];
    __shared__ float xg[18];
    __shared__ float h1r[32];

    if (t < 19) sb[t] = part[(size_t)(2 * b) * 20 + t] + part[(size_t)(2 * b) * 20 + 20 + t];
    // 64 threads = one wave: LDS ops are in-order, no barrier needed
    const float invd = __builtin_amdgcn_rcpf(sb[18]);
    if (t < 18) xg[t] = sb[t] * invd;

    if (t < 32) {
        float h = b0[t];
        #pragma unroll
        for (int k = 0; k < 16; ++k) h = fmaf(xg[k], w0[k * 32 + t], h);
        h = fmaxf(h, 0.01f * h);
        h1r[t] = h;
    }
    if (t < 32) {
        float h = b1[t];
        #pragma unroll
        for (int k = 0; k < 32; ++k) h = fmaf(h1r[k], w1[k * 32 + t], h);
        h = fmaxf(h, 0.01f * h);
        float p = h * w2[t];
        #pragma unroll
        for (int off = 16; off; off >>= 1) p += __shfl_xor(p, off);
        if (t == 0) {
            out[b * 3 + 0] = 1.0f / (1.0f + expf(-(p + b2[0])));
            out[b * 3 + 1] = xg[16];
            out[b * 3 + 2] = xg[17];
        }
    }
}

extern "C" void kernel_launch(void* const* d_in, const int* in_sizes, int n_in,
                              void* d_out, int out_size, void* d_ws, size_t ws_size,
                              hipStream_t stream) {
    const float* pt    = (const float*)d_in[0];
    const float* ang   = (const float*)d_in[1];
    const float* c0_w0 = (const float*)d_in[2];
    const float* c0_b0 = (const float*)d_in[3];
    const float* c0_w1 = (const float*)d_in[4];
    const float* c0_b1 = (const float*)d_in[5];
    const float* c1_w0 = (const float*)d_in[6];
    const float* c1_b0 = (const float*)d_in[7];
    const float* c1_w1 = (const float*)d_in[8];
    const float* c1_b1 = (const float*)d_in[9];
    const float* r_w0  = (const float*)d_in[10];
    const float* r_b0  = (const float*)d_in[11];
    const float* r_w1  = (const float*)d_in[12];
    const float* r_b1  = (const float*)d_in[13];
    const float* r_w2  = (const float*)d_in[14];
    const float* r_b2  = (const float*)d_in[15];
    float* out = (float*)d_out;
    float* partb = (float*)d_ws;               // 256*20 floats

    hipLaunchKernelGGL(fused_kernel, dim3(2 * BB), dim3(1024), 0, stream,
                       pt, ang, c0_w0, c0_b0, c0_w1, c0_b1,
                       c1_w0, c1_b0, c1_w1, c1_b1, partb);
    hipLaunchKernelGGL(readout_kernel, dim3(BB), dim3(64), 0, stream,
                       partb, r_w0, r_b0, r_w1, r_b1, r_w2, r_b2, out);
}

// Round 12
// 49.479 us; speedup vs baseline: 1.0115x; 1.0115x over previous
//
#include <hip/hip_runtime.h>
#include <math.h>

// SMEFTNet forward. B=128, N=128, H=16.  TWO kernels.
// K1 "fused": 256 blocks (batch, ihalf) x 1024 thr (16 waves), 1 block/CU.
//   Phase 0: conv0 for ALL 128 nodes of the batch (duplicated across the
//   batch's two blocks -> zero cross-block deps). Outputs to LDS.
//   Phase 1: conv1 for this block's 64-node half, j-data from LDS.
//   Phase 2: readout partials -> part[block][20].
// K2: 128 blocks x 64 thr: combine 2 partials, 16->32->32->1 MLP -> out.
//
// R10/R11 bug finally diagnosed: with 1024-thr blocks + 29KB LDS the
// allocator targets 2 blocks/CU (8 waves/EU) -> 64 VGPRs -> ~70MB scratch
// spill traffic. launch_bounds' 2nd arg can only LOWER the cap. Fix:
// amdgpu_waves_per_eu(4,4) pins 4 waves/EU -> 128-VGPR budget, no spill.

#define BB 128
#define NN 128
#define BN (BB * NN)

typedef float f32x2 __attribute__((ext_vector_type(2)));

__device__ __forceinline__ f32x2 pk2(float s) { f32x2 r; r[0] = s; r[1] = s; return r; }
__device__ __forceinline__ f32x2 pkfma(f32x2 a, f32x2 b, f32x2 c) {
    return __builtin_elementwise_fma(a, b, c);
}
__device__ __forceinline__ f32x2 pkmax(f32x2 a, f32x2 b) {
    return __builtin_elementwise_max(a, b);
}

template <int CTRL>
__device__ __forceinline__ float dpp_add(float x) {
    int tmp = __builtin_amdgcn_update_dpp(0, __float_as_int(x), CTRL, 0xF, 0xF, true);
    return x + __int_as_float(tmp);
}

// Sum within each 16-lane row; result valid in lane (l|15) of each row.
__device__ __forceinline__ float grp16_sum(float x) {
    x = dpp_add<0xB1>(x);   // quad_perm [1,0,3,2]
    x = dpp_add<0x4E>(x);   // quad_perm [2,3,0,1]
    x = dpp_add<0x114>(x);  // row_shr:4
    x = dpp_add<0x118>(x);  // row_shr:8
    return x;
}

__device__ __forceinline__ float bcast_grp(float x, int bidx) {
    return __int_as_float(__builtin_amdgcn_ds_bpermute(bidx, __float_as_int(x)));
}

__device__ __forceinline__ f32x2 grp16_red2(f32x2 x, int bidx) {
    f32x2 r;
    r[0] = bcast_grp(grp16_sum(x[0]), bidx);
    r[1] = bcast_grp(grp16_sum(x[1]), bidx);
    return r;
}

// ---------------- K1: fused conv0 + conv1 + block partials ----------------
__global__ __attribute__((amdgpu_waves_per_eu(4, 4))) __launch_bounds__(1024)
void fused_kernel(
    const float* __restrict__ pt,    // (B,N)
    const float* __restrict__ ang,   // (B,N,2)
    const float* __restrict__ w0,    // c0_w0 (5,16)
    const float* __restrict__ b0,    // c0_b0 (16)
    const float* __restrict__ w1,    // c0_w1 (16,17)
    const float* __restrict__ b1,    // c0_b1 (17)
    const float* __restrict__ nw0,   // c1_w0 (50,16)
    const float* __restrict__ nb0,   // c1_b0 (16)
    const float* __restrict__ nw1,   // c1_w1 (16,17)
    const float* __restrict__ nb1,   // c1_b1 (17)
    float* __restrict__ part)        // (256,20)
{
    const int tid   = threadIdx.x;
    const int lane  = tid & 63;
    const int wid   = tid >> 6;        // 0..15
    const int t     = lane & 15;
    const int g     = lane >> 4;
    const int batch = blockIdx.x >> 1;
    const int ihalf = blockIdx.x & 1;
    const int nbase = batch * NN;

    __shared__ float u_lds[128][20];
    __shared__ float v_lds[128][20];
    __shared__ float4 rec_lds[128];
    __shared__ float hls[64][20];
    __shared__ float Ap2[16][20];

    // ---- phase 0: conv0 for all 128 nodes (2 rounds of 64) ----
    float2 ajv[8]; float abszj[8], ivjr[8];
    #pragma unroll
    for (int jj = 0; jj < 8; ++jj) {
        ajv[jj] = ((const float2*)ang)[nbase + jj * 16 + t];
        const float r2 = fmaf(ajv[jj].x, ajv[jj].x, ajv[jj].y * ajv[jj].y);
        abszj[jj] = __builtin_amdgcn_sqrtf(r2);
        ivjr[jj]  = __builtin_amdgcn_rsqf(r2);
    }
    // layer-0 constants (uniform addresses -> scalar loads)
    f32x2 q02[8], wc2[8], ws2[8], wac2[8], bb2[8];
    #pragma unroll
    for (int p = 0; p < 8; ++p) {
        f32x2 wa  = *(const f32x2*)(w0 + 2 * p);
        f32x2 wb  = *(const f32x2*)(w0 + 16 + 2 * p);
        f32x2 wcv = *(const f32x2*)(w0 + 32 + 2 * p);
        bb2[p]  = *(const f32x2*)(b0 + 2 * p);
        wac2[p] = wa - wcv;                      // Wa-Wc
        q02[p]  = wb + wcv;                      // Wb+Wc
        wc2[p]  = *(const f32x2*)(w0 + 48 + 2 * p);
        ws2[p]  = *(const f32x2*)(w0 + 64 + 2 * p);
    }

    const int o = lane & 31;
    const int kk = o & 15;
    const bool isU = (o < 16);
    const int bidx = (lane | 15) << 2;

    // proj weights (hoisted: same for both rounds)
    float wkp[16];
    {
        const int off = isU ? 0 : 256;
        #pragma unroll
        for (int c = 0; c < 16; ++c) {
            const float a_ = nw0[off + c * 16 + kk];
            const float c_ = nw0[512 + c * 16 + kk];
            wkp[c] = isU ? (a_ - c_) : (a_ + c_);
        }
    }
    const float accb = isU ? nb0[kk] : 0.0f;

    #pragma unroll
    for (int r = 0; r < 2; ++r) {
        const int nlr    = wid * 4 + g;          // round-local node [0,64)
        const int nlocal = r * 64 + nlr;
        const int ni     = nbase + nlocal;

        const float2 ai = ((const float2*)ang)[ni];
        const float r2i = fmaf(ai.x, ai.x, ai.y * ai.y);
        const float abszi = __builtin_amdgcn_sqrtf(r2i);
        const float invi  = __builtin_amdgcn_rsqf(r2i);

        f32x2 u0b2[8];
        #pragma unroll
        for (int p = 0; p < 8; ++p) u0b2[p] = pkfma(pk2(abszi), wac2[p], bb2[p]);

        f32x2 A2[8];
        #pragma unroll
        for (int p = 0; p < 8; ++p) A2[p] = pk2(0.0f);
        float degf = 0.0f;

        #pragma unroll
        for (int jj = 0; jj < 8; ++jj) {
            const float2 aj = ajv[jj];
            const float dre = ai.x - aj.x, dim = ai.y - aj.y;
            const float d2 = fmaf(dre, dre, dim * dim);
            const float adjf = (d2 <= 0.16f) ? 1.0f : 0.0f;
            degf += adjf;
            const float inv = fminf(invi * ivjr[jj], 1e12f);
            const f32x2 cos2 = pk2(fmaf(ai.x, aj.x, ai.y * aj.y) * inv);
            const f32x2 sin2 = pk2(fmaf(ai.y, aj.x, -(ai.x * aj.y)) * inv);
            const f32x2 ab2 = pk2(abszj[jj]);
            const f32x2 adj2 = pk2(adjf);
            #pragma unroll
            for (int p = 0; p < 8; ++p) {
                f32x2 z = pkfma(ab2, q02[p], u0b2[p]);
                z = pkfma(cos2, wc2[p], z);
                z = pkfma(sin2, ws2[p], z);
                f32x2 a = pkmax(z, z * 0.01f);
                A2[p] = pkfma(a, adj2, A2[p]);
            }
        }

        f32x2 Ak2[8];
        #pragma unroll
        for (int p = 0; p < 8; ++p) Ak2[p] = grp16_red2(A2[p], bidx);
        const float invdeg = __builtin_amdgcn_rcpf(bcast_grp(grp16_sum(degf), bidx));

        // 2nd MLP layer (epilogue loads: channel t + gamma column)
        f32x2 s2 = pk2(0.0f), g2 = pk2(0.0f);
        #pragma unroll
        for (int p = 0; p < 8; ++p) {
            f32x2 wr; wr[0] = w1[(2 * p) * 17 + t];  wr[1] = w1[(2 * p + 1) * 17 + t];
            f32x2 wg; wg[0] = w1[(2 * p) * 17 + 16]; wg[1] = w1[(2 * p + 1) * 17 + 16];
            s2 = pkfma(Ak2[p], wr, s2);
            g2 = pkfma(Ak2[p], wg, g2);
        }
        const float mt    = fmaf(s2[0] + s2[1], invdeg, b1[t]);
        const float gamma = fmaf(g2[0] + g2[1], invdeg, b1[16]);

        // rotation (v_cos/v_sin take revolutions); norm preserved -> store invi
        {
            const float gf = gamma - floorf(gamma);
            const float cs = __builtin_amdgcn_cosf(gf);
            const float sn = __builtin_amdgcn_sinf(gf);
            if (t == 0) {
                const float re2 = cs * ai.x - sn * ai.y;
                const float im2 = fmaf(sn, ai.x, cs * ai.y);
                rec_lds[nlocal] = make_float4(re2, im2, invi, 0.0f);
            }
        }

        hls[nlr][t] = mt;   // same-wave exchange (in-order, no barrier)

        #pragma unroll
        for (int ps = 0; ps < 2; ++ps) {
            const int nl = (lane >> 5) + 2 * ps;
            const int node = wid * 4 + nl;       // round-local
            float acc = accb;
            #pragma unroll
            for (int c = 0; c < 16; ++c) acc = fmaf(hls[node][c], wkp[c], acc);
            if (isU) u_lds[r * 64 + node][kk] = acc;
            else     v_lds[r * 64 + node][kk] = acc;
        }
    }
    __syncthreads();

    // ---- phase 1: conv1 for this block's 64-node half ----
    const int nlocal1 = ihalf * 64 + wid * 4 + g;
    const int ni1 = nbase + nlocal1;
    const float4 a4 = rec_lds[nlocal1];
    const float rei = a4.x, imi = a4.y, invi1 = a4.z;
    const float ptf = pt[ni1];

    f32x2 u0b2[8];
    {
        const float4* ug = (const float4*)&u_lds[nlocal1][0];
        float4 q0 = ug[0], q1 = ug[1], q2 = ug[2], q3 = ug[3];
        u0b2[0][0] = q0.x; u0b2[0][1] = q0.y; u0b2[1][0] = q0.z; u0b2[1][1] = q0.w;
        u0b2[2][0] = q1.x; u0b2[2][1] = q1.y; u0b2[3][0] = q1.z; u0b2[3][1] = q1.w;
        u0b2[4][0] = q2.x; u0b2[4][1] = q2.y; u0b2[5][0] = q2.z; u0b2[5][1] = q2.w;
        u0b2[6][0] = q3.x; u0b2[6][1] = q3.y; u0b2[7][0] = q3.z; u0b2[7][1] = q3.w;
    }
    f32x2 wc1[8], ws1[8];   // uniform -> scalar loads
    #pragma unroll
    for (int p = 0; p < 8; ++p) {
        wc1[p] = *(const f32x2*)(nw0 + 768 + 2 * p);
        ws1[p] = *(const f32x2*)(nw0 + 784 + 2 * p);
    }

    f32x2 A2[8];
    #pragma unroll
    for (int p = 0; p < 8; ++p) A2[p] = pk2(0.0f);
    float degf = 0.0f;

    #pragma unroll 4
    for (int jj = 0; jj < 8; ++jj) {
        const int j = jj * 16 + t;
        const float4 rj = rec_lds[j];
        f32x2 vj2[8];
        {
            const float4* vg = (const float4*)&v_lds[j][0];
            float4 q0 = vg[0], q1 = vg[1], q2 = vg[2], q3 = vg[3];
            vj2[0][0] = q0.x; vj2[0][1] = q0.y; vj2[1][0] = q0.z; vj2[1][1] = q0.w;
            vj2[2][0] = q1.x; vj2[2][1] = q1.y; vj2[3][0] = q1.z; vj2[3][1] = q1.w;
            vj2[4][0] = q2.x; vj2[4][1] = q2.y; vj2[5][0] = q2.z; vj2[5][1] = q2.w;
            vj2[6][0] = q3.x; vj2[6][1] = q3.y; vj2[7][0] = q3.z; vj2[7][1] = q3.w;
        }
        const float dre = rei - rj.x, dim = imi - rj.y;
        const float d2 = fmaf(dre, dre, dim * dim);
        const float adjf = (d2 <= 0.16f) ? 1.0f : 0.0f;
        degf += adjf;
        const float inv = fminf(invi1 * rj.z, 1e12f);
        const f32x2 cos2 = pk2(fmaf(rei, rj.x, imi * rj.y) * inv);
        const f32x2 sin2 = pk2(fmaf(imi, rj.x, -(rei * rj.y)) * inv);
        const f32x2 adj2 = pk2(adjf);
        #pragma unroll
        for (int p = 0; p < 8; ++p) {
            f32x2 z = u0b2[p] + vj2[p];
            z = pkfma(cos2, wc1[p], z);
            z = pkfma(sin2, ws1[p], z);
            f32x2 a = pkmax(z, z * 0.01f);
            A2[p] = pkfma(a, adj2, A2[p]);
        }
    }

    f32x2 Ak2[8];
    #pragma unroll
    for (int p = 0; p < 8; ++p) Ak2[p] = grp16_red2(A2[p], bidx);
    const float invdeg = __builtin_amdgcn_rcpf(bcast_grp(grp16_sum(degf), bidx));

    f32x2 s2 = pk2(0.0f), g2 = pk2(0.0f);
    #pragma unroll
    for (int p = 0; p < 8; ++p) {
        f32x2 wr; wr[0] = nw1[(2 * p) * 17 + t];  wr[1] = nw1[(2 * p + 1) * 17 + t];
        f32x2 wg; wg[0] = nw1[(2 * p) * 17 + 16]; wg[1] = nw1[(2 * p + 1) * 17 + 16];
        s2 = pkfma(Ak2[p], wr, s2);
        g2 = pkfma(Ak2[p], wg, g2);
    }
    const float mt    = fmaf(s2[0] + s2[1], invdeg, nb1[t]);
    const float gamma = fmaf(g2[0] + g2[1], invdeg, nb1[16]);

    const float gf = gamma - floorf(gamma);
    const float cs = __builtin_amdgcn_cosf(gf);
    const float sn = __builtin_amdgcn_sinf(gf);
    const float re2 = cs * rei - sn * imi;
    const float im2 = fmaf(sn, rei, cs * imi);

    // ---- phase 2: readout partials ----
    float pm  = ptf * mt;
    float pre = ptf * re2;
    float pim = ptf * im2;
    float ppt = ptf;
    pm  += __int_as_float(__builtin_amdgcn_ds_swizzle(__float_as_int(pm),  0x401F));
    pre += __int_as_float(__builtin_amdgcn_ds_swizzle(__float_as_int(pre), 0x401F));
    pim += __int_as_float(__builtin_amdgcn_ds_swizzle(__float_as_int(pim), 0x401F));
    ppt += __int_as_float(__builtin_amdgcn_ds_swizzle(__float_as_int(ppt), 0x401F));
    pm  += __shfl_xor(pm, 32);
    pre += __shfl_xor(pre, 32);
    pim += __shfl_xor(pim, 32);
    ppt += __shfl_xor(ppt, 32);

    if (lane < 16)       Ap2[wid][lane] = pm;
    else if (lane == 16) Ap2[wid][16] = pre;
    else if (lane == 17) Ap2[wid][17] = pim;
    else if (lane == 18) Ap2[wid][18] = ppt;
    __syncthreads();

    if (wid == 0 && lane < 19) {
        float s0 = 0.0f, s1 = 0.0f, s2_ = 0.0f, s3 = 0.0f;
        #pragma unroll
        for (int w = 0; w < 16; w += 4) {
            s0 += Ap2[w + 0][lane];
            s1 += Ap2[w + 1][lane];
            s2_ += Ap2[w + 2][lane];
            s3 += Ap2[w + 3][lane];
        }
        part[(size_t)blockIdx.x * 20 + lane] = (s0 + s1) + (s2_ + s3);
    }
}

// ---------------- K2: final readout (1 wave per batch) ----------------
__global__ __launch_bounds__(64) void readout_kernel(
    const float* __restrict__ part,  // (256,20)
    const float* __restrict__ w0, const float* __restrict__ b0,  // (16,32),(32)
    const float* __restrict__ w1, const float* __restrict__ b1,  // (32,32),(32)
    const float* __restrict__ w2, const float* __restrict__ b2,  // (32,1),(1)
    float* __restrict__ out) {
    const int b = blockIdx.x;
    const int t = threadIdx.x;

    __shared__ float sb[19];
    __shared__ float xg[18];
    __shared__ float h1r[32];

    if (t < 19) sb[t] = part[(size_t)(2 * b) * 20 + t] + part[(size_t)(2 * b) * 20 + 20 + t];
    // 64 threads = one wave: LDS ops are in-order, no barrier needed
    const float invd = __builtin_amdgcn_rcpf(sb[18]);
    if (t < 18) xg[t] = sb[t] * invd;

    if (t < 32) {
        float h = b0[t];
        #pragma unroll
        for (int k = 0; k < 16; ++k) h = fmaf(xg[k], w0[k * 32 + t], h);
        h = fmaxf(h, 0.01f * h);
        h1r[t] = h;
    }
    if (t < 32) {
        float h = b1[t];
        #pragma unroll
        for (int k = 0; k < 32; ++k) h = fmaf(h1r[k], w1[k * 32 + t], h);
        h = fmaxf(h, 0.01f * h);
        float p = h * w2[t];
        #pragma unroll
        for (int off = 16; off; off >>= 1) p += __shfl_xor(p, off);
        if (t == 0) {
            out[b * 3 + 0] = 1.0f / (1.0f + expf(-(p + b2[0])));
            out[b * 3 + 1] = xg[16];
            out[b * 3 + 2] = xg[17];
        }
    }
}

extern "C" void kernel_launch(void* const* d_in, const int* in_sizes, int n_in,
                              void* d_out, int out_size, void* d_ws, size_t ws_size,
                              hipStream_t stream) {
    const float* pt    = (const float*)d_in[0];
    const float* ang   = (const float*)d_in[1];
    const float* c0_w0 = (const float*)d_in[2];
    const float* c0_b0 = (const float*)d_in[3];
    const float* c0_w1 = (const float*)d_in[4];
    const float* c0_b1 = (const float*)d_in[5];
    const float* c1_w0 = (const float*)d_in[6];
    const float* c1_b0 = (const float*)d_in[7];
    const float* c1_w1 = (const float*)d_in[8];
    const float* c1_b1 = (const float*)d_in[9];
    const float* r_w0  = (const float*)d_in[10];
    const float* r_b0  = (const float*)d_in[11];
    const float* r_w1  = (const float*)d_in[12];
    const float* r_b1  = (const float*)d_in[13];
    const float* r_w2  = (const float*)d_in[14];
    const float* r_b2  = (const float*)d_in[15];
    float* out = (float*)d_out;
    float* partb = (float*)d_ws;               // 256*20 floats

    hipLaunchKernelGGL(fused_kernel, dim3(2 * BB), dim3(1024), 0, stream,
                       pt, ang, c0_w0, c0_b0, c0_w1, c0_b1,
                       c1_w0, c1_b0, c1_w1, c1_b1, partb);
    hipLaunchKernelGGL(readout_kernel, dim3(BB), dim3(64), 0, stream,
                       partb, r_w0, r_b0, r_w1, r_b1, r_w2, r_b2, out);
}

// Round 13
// 30.168 us; speedup vs baseline: 1.6589x; 1.6401x over previous
//
#include <hip/hip_runtime.h>
#include <math.h>

// SMEFTNet forward. B=128, N=128, H=16.  "Config Y": 4 nodes per wave.
// (Exact reproduction of the verified 30.2us best from R6.)
// lane = g*16 + t:  g = node-subgroup (wave handles nodes wid*4+g), t = channel.
// j-loop: 8 iters, lane handles pair (node_g, j = 16*jj + t).
// Reduce: 4-step DPP tree within 16-lane rows + ds_bpermute broadcast from
// lane (l|15) -> every lane gets its node's channel sums. deg = 17th chain.
// conv0 epilogue: 2nd layer (one FMA pass, all lanes), gamma pass (SGPR w1
// col 16), rotation per-lane (t==0 stores float4 ang1 = re,im,inv), proj to
// u1/v1 via LDS h-exchange (same-wave, no barrier) + 2 full-wave passes.
// conv1 epilogue: same + per-wave readout partials (xor16 swizzle + xor32
// shfl over groups) -> part[4096][20]. K3: 1 wave/batch sums 32 partial rows,
// then the 16->32->32->1 readout MLP.

#define BB 128
#define NN 128
#define BN (BB * NN)

typedef float f32x2 __attribute__((ext_vector_type(2)));

__device__ __forceinline__ f32x2 pk2(float s) { f32x2 r; r[0] = s; r[1] = s; return r; }
__device__ __forceinline__ f32x2 pkfma(f32x2 a, f32x2 b, f32x2 c) {
    return __builtin_elementwise_fma(a, b, c);
}
__device__ __forceinline__ f32x2 pkmax(f32x2 a, f32x2 b) {
    return __builtin_elementwise_max(a, b);
}

template <int CTRL>
__device__ __forceinline__ float dpp_add(float x) {
    int tmp = __builtin_amdgcn_update_dpp(0, __float_as_int(x), CTRL, 0xF, 0xF, true);
    return x + __int_as_float(tmp);
}

// Sum within each 16-lane row; result valid in lane (l|15) of each row.
__device__ __forceinline__ float grp16_sum(float x) {
    x = dpp_add<0xB1>(x);   // quad_perm [1,0,3,2]  (xor 1)
    x = dpp_add<0x4E>(x);   // quad_perm [2,3,0,1]  (xor 2)
    x = dpp_add<0x114>(x);  // row_shr:4
    x = dpp_add<0x118>(x);  // row_shr:8
    return x;
}

__device__ __forceinline__ float bcast_grp(float x, int bidx) {
    return __int_as_float(__builtin_amdgcn_ds_bpermute(bidx, __float_as_int(x)));
}

// ---------------- K1: conv0 + fused proj for conv1 ----------------
__global__ __launch_bounds__(256) void conv0_kernel(
    const float* __restrict__ ang,   // (B,N,2)
    const float* __restrict__ w0,    // c0_w0 (5,16)
    const float* __restrict__ b0,    // (16)
    const float* __restrict__ w1,    // c0_w1 (16,17)
    const float* __restrict__ b1,    // (17)
    const float* __restrict__ nw0,   // c1_w0 (50,16)
    const float* __restrict__ nb0,   // c1_b0 (16)
    float* __restrict__ ang1,        // (BN,4): re,im,inv,0
    float* __restrict__ u1,          // (BN,16)
    float* __restrict__ v1)          // (BN,16)
{
    const int tid  = threadIdx.x;
    const int lane = tid & 63;
    const int wid  = tid >> 6;
    const int t    = lane & 15;      // channel / j-sub-index
    const int g    = lane >> 4;      // node subgroup 0..3
    const int ni   = blockIdx.x * 16 + wid * 4 + g;
    const int base = (blockIdx.x >> 3) << 7;   // batch start node

    __shared__ float hls[16][17];

    // my node
    const float2 ai = ((const float2*)ang)[ni];
    const float r2i = fmaf(ai.x, ai.x, ai.y * ai.y);
    const float abszi = __builtin_amdgcn_sqrtf(r2i);
    const float invi  = __builtin_amdgcn_rsqf(r2i);

    // layer-0 row constants (wave-uniform -> s_load) + per-lane u0b
    f32x2 u0b2[8], q02[8], wc2[8], ws2[8];
    #pragma unroll
    for (int p = 0; p < 8; ++p) {
        f32x2 wa  = *(const f32x2*)(w0 + 2 * p);
        f32x2 wb  = *(const f32x2*)(w0 + 16 + 2 * p);
        f32x2 wcv = *(const f32x2*)(w0 + 32 + 2 * p);
        f32x2 bb  = *(const f32x2*)(b0 + 2 * p);
        u0b2[p] = pkfma(pk2(abszi), wa - wcv, bb);   // absz_i*(Wa-Wc)+b0
        q02[p]  = wb + wcv;                          // Wb+Wc
        wc2[p]  = *(const f32x2*)(w0 + 48 + 2 * p);
        ws2[p]  = *(const f32x2*)(w0 + 64 + 2 * p);
    }

    // prefetch w1 column t (per-lane) and gamma column (uniform)
    float w1row[16], w1g[16];
    #pragma unroll
    for (int k = 0; k < 16; ++k) {
        w1row[k] = w1[k * 17 + t];
        w1g[k]   = w1[k * 17 + 16];
    }
    const float b1t = b1[t], b1g = b1[16];

    // prefetch + combine proj weights: output o = lane&31 (k = o&15, u/v half)
    const int o   = lane & 31;
    const int kk  = o & 15;
    const bool isU = (o < 16);
    float wk[16];
    {
        const int off = isU ? 0 : 256;
        #pragma unroll
        for (int c = 0; c < 16; ++c) {
            float a_ = nw0[off + c * 16 + kk];
            float c_ = nw0[512 + c * 16 + kk];
            wk[c] = isU ? (a_ - c_) : (a_ + c_);
        }
    }
    const float accb = isU ? nb0[kk] : 0.0f;

    // j-loop: 8 iters, j = 16*jj + t
    f32x2 A2[8];
    #pragma unroll
    for (int p = 0; p < 8; ++p) A2[p] = pk2(0.0f);
    float degf = 0.0f;

    #pragma unroll 4
    for (int jj = 0; jj < 8; ++jj) {
        const float2 aj = ((const float2*)ang)[base + jj * 16 + t];
        const float r2j = fmaf(aj.x, aj.x, aj.y * aj.y);
        const float abszj = __builtin_amdgcn_sqrtf(r2j);
        const float ivj   = __builtin_amdgcn_rsqf(r2j);
        const float dre = ai.x - aj.x, dim = ai.y - aj.y;
        const float d2 = fmaf(dre, dre, dim * dim);
        const float adjf = (d2 <= 0.16f) ? 1.0f : 0.0f;
        degf += adjf;
        const float inv = fminf(invi * ivj, 1e12f);
        const f32x2 cos2 = pk2(fmaf(ai.x, aj.x, ai.y * aj.y) * inv);
        const f32x2 sin2 = pk2(fmaf(ai.y, aj.x, -(ai.x * aj.y)) * inv);
        const f32x2 ab2 = pk2(abszj);
        const f32x2 adj2 = pk2(adjf);
        #pragma unroll
        for (int p = 0; p < 8; ++p) {
            f32x2 z = pkfma(ab2, q02[p], u0b2[p]);
            z = pkfma(cos2, wc2[p], z);
            z = pkfma(sin2, ws2[p], z);
            f32x2 a = pkmax(z, z * 0.01f);
            A2[p] = pkfma(a, adj2, A2[p]);
        }
    }

    // reduce: 17 chains, 4-step DPP + bpermute broadcast from lane (l|15)
    const int bidx = (lane | 15) << 2;
    float Ak[16];
    #pragma unroll
    for (int p = 0; p < 8; ++p) {
        Ak[2 * p]     = bcast_grp(grp16_sum(A2[p][0]), bidx);
        Ak[2 * p + 1] = bcast_grp(grp16_sum(A2[p][1]), bidx);
    }
    const float degA = bcast_grp(grp16_sum(degf), bidx);
    const float invdeg = __builtin_amdgcn_rcpf(degA);

    // 2nd MLP layer: channel t (per-lane weights) + gamma (SGPR weights)
    float s = 0.0f, sg = 0.0f;
    #pragma unroll
    for (int k = 0; k < 16; ++k) {
        s  = fmaf(Ak[k], w1row[k], s);
        sg = fmaf(Ak[k], w1g[k], sg);
    }
    const float mt    = fmaf(s, invdeg, b1t);
    const float gamma = fmaf(sg, invdeg, b1g);

    // rotation (v_cos/v_sin take revolutions); norm preserved -> store invi
    {
        const float gf = gamma - floorf(gamma);
        const float cs = __builtin_amdgcn_cosf(gf);
        const float sn = __builtin_amdgcn_sinf(gf);
        const float re2 = cs * ai.x - sn * ai.y;
        const float im2 = fmaf(sn, ai.x, cs * ai.y);
        if (t == 0) ((float4*)ang1)[ni] = make_float4(re2, im2, invi, 0.0f);
    }

    // h-exchange (same-wave LDS, no barrier needed)
    hls[wid * 4 + g][t] = mt;

    // proj: 2 passes x 64 lanes = 128 outputs (4 nodes x (16 u + 16 v))
    #pragma unroll
    for (int p = 0; p < 2; ++p) {
        const int nl = (lane >> 5) + 2 * p;       // node local 0..3
        const int node = wid * 4 + nl;
        float acc = accb;
        #pragma unroll
        for (int c = 0; c < 16; ++c) acc = fmaf(hls[node][c], wk[c], acc);
        const int nout = (blockIdx.x * 16 + node);
        if (isU) u1[nout * 16 + kk] = acc;
        else     v1[nout * 16 + kk] = acc;
    }
}

// ---------------- K2: conv1 + per-wave readout partials ----------------
__global__ __launch_bounds__(256) void conv1_kernel(
    const float* __restrict__ pt,    // (B,N)
    const float* __restrict__ ang1,  // (BN,4): re,im,inv,0
    const float* __restrict__ u1,    // (BN,16)
    const float* __restrict__ v1,    // (BN,16)
    const float* __restrict__ w0,    // c1_w0 (50,16)
    const float* __restrict__ w1,    // c1_w1 (16,17)
    const float* __restrict__ b1,    // (17)
    float* __restrict__ part)        // (4096,20): [0..15]=sum pt*m, 16=re,17=im,18=sum pt
{
    const int tid  = threadIdx.x;
    const int lane = tid & 63;
    const int wid  = tid >> 6;
    const int t    = lane & 15;
    const int g    = lane >> 4;
    const int ni   = blockIdx.x * 16 + wid * 4 + g;
    const int base = (blockIdx.x >> 3) << 7;

    // my node
    const float4 a4 = ((const float4*)ang1)[ni];
    const float rei = a4.x, imi = a4.y, invi = a4.z;
    const float ptf = pt[ni];

    f32x2 u0b2[8], wc2[8], ws2[8];
    {
        const float4* ug = (const float4*)(u1 + (size_t)ni * 16);
        float4 q0 = ug[0], q1 = ug[1], q2 = ug[2], q3 = ug[3];
        u0b2[0][0] = q0.x; u0b2[0][1] = q0.y; u0b2[1][0] = q0.z; u0b2[1][1] = q0.w;
        u0b2[2][0] = q1.x; u0b2[2][1] = q1.y; u0b2[3][0] = q1.z; u0b2[3][1] = q1.w;
        u0b2[4][0] = q2.x; u0b2[4][1] = q2.y; u0b2[5][0] = q2.z; u0b2[5][1] = q2.w;
        u0b2[6][0] = q3.x; u0b2[6][1] = q3.y; u0b2[7][0] = q3.z; u0b2[7][1] = q3.w;
    }
    #pragma unroll
    for (int p = 0; p < 8; ++p) {
        wc2[p] = *(const f32x2*)(w0 + 768 + 2 * p);
        ws2[p] = *(const f32x2*)(w0 + 784 + 2 * p);
    }

    float w1row[16], w1g[16];
    #pragma unroll
    for (int k = 0; k < 16; ++k) {
        w1row[k] = w1[k * 17 + t];
        w1g[k]   = w1[k * 17 + 16];
    }
    const float b1t = b1[t], b1g = b1[16];

    f32x2 A2[8];
    #pragma unroll
    for (int p = 0; p < 8; ++p) A2[p] = pk2(0.0f);
    float degf = 0.0f;

    #pragma unroll 4
    for (int jj = 0; jj < 8; ++jj) {
        const int j = base + jj * 16 + t;
        const float4 aj = ((const float4*)ang1)[j];
        f32x2 vj2[8];
        {
            const float4* vg = (const float4*)(v1 + (size_t)j * 16);
            float4 q0 = vg[0], q1 = vg[1], q2 = vg[2], q3 = vg[3];
            vj2[0][0] = q0.x; vj2[0][1] = q0.y; vj2[1][0] = q0.z; vj2[1][1] = q0.w;
            vj2[2][0] = q1.x; vj2[2][1] = q1.y; vj2[3][0] = q1.z; vj2[3][1] = q1.w;
            vj2[4][0] = q2.x; vj2[4][1] = q2.y; vj2[5][0] = q2.z; vj2[5][1] = q2.w;
            vj2[6][0] = q3.x; vj2[6][1] = q3.y; vj2[7][0] = q3.z; vj2[7][1] = q3.w;
        }
        const float dre = rei - aj.x, dim = imi - aj.y;
        const float d2 = fmaf(dre, dre, dim * dim);
        const float adjf = (d2 <= 0.16f) ? 1.0f : 0.0f;
        degf += adjf;
        const float inv = fminf(invi * aj.z, 1e12f);
        const f32x2 cos2 = pk2(fmaf(rei, aj.x, imi * aj.y) * inv);
        const f32x2 sin2 = pk2(fmaf(imi, aj.x, -(rei * aj.y)) * inv);
        const f32x2 adj2 = pk2(adjf);
        #pragma unroll
        for (int p = 0; p < 8; ++p) {
            f32x2 z = u0b2[p] + vj2[p];
            z = pkfma(cos2, wc2[p], z);
            z = pkfma(sin2, ws2[p], z);
            f32x2 a = pkmax(z, z * 0.01f);
            A2[p] = pkfma(a, adj2, A2[p]);
        }
    }

    const int bidx = (lane | 15) << 2;
    float Ak[16];
    #pragma unroll
    for (int p = 0; p < 8; ++p) {
        Ak[2 * p]     = bcast_grp(grp16_sum(A2[p][0]), bidx);
        Ak[2 * p + 1] = bcast_grp(grp16_sum(A2[p][1]), bidx);
    }
    const float degA = bcast_grp(grp16_sum(degf), bidx);
    const float invdeg = __builtin_amdgcn_rcpf(degA);

    float s = 0.0f, sg = 0.0f;
    #pragma unroll
    for (int k = 0; k < 16; ++k) {
        s  = fmaf(Ak[k], w1row[k], s);
        sg = fmaf(Ak[k], w1g[k], sg);
    }
    const float mt    = fmaf(s, invdeg, b1t);
    const float gamma = fmaf(sg, invdeg, b1g);

    const float gf = gamma - floorf(gamma);
    const float cs = __builtin_amdgcn_cosf(gf);
    const float sn = __builtin_amdgcn_sinf(gf);
    const float re2 = cs * rei - sn * imi;
    const float im2 = fmaf(sn, rei, cs * imi);

    // per-wave readout partials: sum over the wave's 4 nodes.
    float pm  = ptf * mt;     // per-channel t
    float pre = ptf * re2;    // uniform within group
    float pim = ptf * im2;
    float ppt = ptf;
    // cross-group sum: xor16 (ds_swizzle) + xor32 (shfl)
    pm  += __int_as_float(__builtin_amdgcn_ds_swizzle(__float_as_int(pm),  0x401F));
    pre += __int_as_float(__builtin_amdgcn_ds_swizzle(__float_as_int(pre), 0x401F));
    pim += __int_as_float(__builtin_amdgcn_ds_swizzle(__float_as_int(pim), 0x401F));
    ppt += __int_as_float(__builtin_amdgcn_ds_swizzle(__float_as_int(ppt), 0x401F));
    pm  += __shfl_xor(pm, 32);
    pre += __shfl_xor(pre, 32);
    pim += __shfl_xor(pim, 32);
    ppt += __shfl_xor(ppt, 32);

    float* po = part + (size_t)(blockIdx.x * 4 + wid) * 20;
    if (lane < 16)       po[lane] = pm;
    else if (lane == 16) po[16] = pre;
    else if (lane == 17) po[17] = pim;
    else if (lane == 18) po[18] = ppt;
}

// ---------------- K3: final readout (1 wave per batch) ----------------
__global__ __launch_bounds__(64) void readout_kernel(
    const float* __restrict__ part,  // (4096,20)
    const float* __restrict__ w0, const float* __restrict__ b0,  // (16,32),(32)
    const float* __restrict__ w1, const float* __restrict__ b1,  // (32,32),(32)
    const float* __restrict__ w2, const float* __restrict__ b2,  // (32,1),(1)
    float* __restrict__ out) {
    const int b = blockIdx.x;
    const int t = threadIdx.x;

    __shared__ float sbuf[19];
    __shared__ float xg[18];
    __shared__ float h1r[32];

    if (t < 19) {
        float s0 = 0.0f, s1 = 0.0f, s2 = 0.0f, s3 = 0.0f;
        const float* pb = part + (size_t)b * 32 * 20 + t;
        #pragma unroll
        for (int r = 0; r < 32; r += 4) {
            s0 += pb[(r + 0) * 20];
            s1 += pb[(r + 1) * 20];
            s2 += pb[(r + 2) * 20];
            s3 += pb[(r + 3) * 20];
        }
        sbuf[t] = (s0 + s1) + (s2 + s3);
    }
    // same wave: LDS ops are in-order, no barrier needed
    const float invd = __builtin_amdgcn_rcpf(sbuf[18]);
    if (t < 18) xg[t] = sbuf[t] * invd;

    if (t < 32) {
        float h = b0[t];
        #pragma unroll
        for (int k = 0; k < 16; ++k) h = fmaf(xg[k], w0[k * 32 + t], h);
        h = fmaxf(h, 0.01f * h);
        h1r[t] = h;
    }
    if (t < 32) {
        float h = b1[t];
        #pragma unroll
        for (int k = 0; k < 32; ++k) h = fmaf(h1r[k], w1[k * 32 + t], h);
        h = fmaxf(h, 0.01f * h);
        float p = h * w2[t];
        #pragma unroll
        for (int off = 16; off; off >>= 1) p += __shfl_xor(p, off);
        if (t == 0) {
            out[b * 3 + 0] = 1.0f / (1.0f + expf(-(p + b2[0])));
            out[b * 3 + 1] = xg[16];
            out[b * 3 + 2] = xg[17];
        }
    }
}

extern "C" void kernel_launch(void* const* d_in, const int* in_sizes, int n_in,
                              void* d_out, int out_size, void* d_ws, size_t ws_size,
                              hipStream_t stream) {
    const float* pt    = (const float*)d_in[0];
    const float* ang   = (const float*)d_in[1];
    const float* c0_w0 = (const float*)d_in[2];
    const float* c0_b0 = (const float*)d_in[3];
    const float* c0_w1 = (const float*)d_in[4];
    const float* c0_b1 = (const float*)d_in[5];
    const float* c1_w0 = (const float*)d_in[6];
    const float* c1_b0 = (const float*)d_in[7];
    const float* c1_w1 = (const float*)d_in[8];
    const float* c1_b1 = (const float*)d_in[9];
    const float* r_w0  = (const float*)d_in[10];
    const float* r_b0  = (const float*)d_in[11];
    const float* r_w1  = (const float*)d_in[12];
    const float* r_b1  = (const float*)d_in[13];
    const float* r_w2  = (const float*)d_in[14];
    const float* r_b2  = (const float*)d_in[15];
    float* out = (float*)d_out;
    float* ws = (float*)d_ws;

    float* ang1  = ws;                         // BN*4
    float* u1    = ang1 + (size_t)BN * 4;      // BN*16
    float* v1    = u1 + (size_t)BN * 16;       // BN*16
    float* partb = v1 + (size_t)BN * 16;       // 4096*20

    hipLaunchKernelGGL(conv0_kernel, dim3(BN / 16), dim3(256), 0, stream,
                       ang, c0_w0, c0_b0, c0_w1, c0_b1, c1_w0, c1_b0,
                       ang1, u1, v1);
    hipLaunchKernelGGL(conv1_kernel, dim3(BN / 16), dim3(256), 0, stream,
                       pt, ang1, u1, v1, c1_w0, c1_w1, c1_b1, partb);
    hipLaunchKernelGGL(readout_kernel, dim3(BB), dim3(64), 0, stream,
                       partb, r_w0, r_b0, r_w1, r_b1, r_w2, r_b2, out);
}